// Round 1
// baseline (1640.643 us; speedup 1.0000x reference)
//
#include <hip/hip_runtime.h>

#define N_NODES_C 500000
#define BS 100000
#define BQ 20000          // BS / 5

constexpr int SCAN_T = 1024;

__device__ __forceinline__ float relu_(float v) { return fmaxf(v, 0.0f); }

// ---------------- CSR build ----------------

__global__ void hist_kernel(const int* __restrict__ dst, int* __restrict__ counts, int E) {
    int i = blockIdx.x * blockDim.x + threadIdx.x;
    int stride = gridDim.x * blockDim.x;
    for (; i < E; i += stride) atomicAdd(&counts[dst[i]], 1);
}

__global__ void scan1_kernel(const int* __restrict__ counts, int n,
                             int* __restrict__ offsets, int* __restrict__ bsums) {
    __shared__ int s[SCAN_T];
    int t = threadIdx.x;
    int g = blockIdx.x * SCAN_T + t;
    int v = (g < n) ? counts[g] : 0;
    s[t] = v;
    __syncthreads();
    for (int d = 1; d < SCAN_T; d <<= 1) {
        int x = (t >= d) ? s[t - d] : 0;
        __syncthreads();
        s[t] += x;
        __syncthreads();
    }
    if (g < n) offsets[g] = s[t] - v;   // exclusive within block
    if (t == SCAN_T - 1) bsums[blockIdx.x] = s[t];
}

__global__ void scan2_kernel(const int* __restrict__ bsums, int n, int* __restrict__ boffs) {
    __shared__ int s[512];
    int t = threadIdx.x;
    int v = (t < n) ? bsums[t] : 0;
    s[t] = v;
    __syncthreads();
    for (int d = 1; d < 512; d <<= 1) {
        int x = (t >= d) ? s[t - d] : 0;
        __syncthreads();
        s[t] += x;
        __syncthreads();
    }
    if (t < n) boffs[t] = s[t] - v;
}

__global__ void scan3_kernel(int* __restrict__ offsets, const int* __restrict__ boffs,
                             int n, int total) {
    int t = threadIdx.x;
    int g = blockIdx.x * SCAN_T + t;
    if (g < n) offsets[g] += boffs[blockIdx.x];
    if (g == 0) offsets[n] = total;
}

__global__ void fill_kernel(const int* __restrict__ src, const int* __restrict__ dst,
                            const float* __restrict__ w, int E,
                            const int* __restrict__ offsets, int* __restrict__ cursor,
                            int* __restrict__ csr_src, float* __restrict__ csr_w) {
    int i = blockIdx.x * blockDim.x + threadIdx.x;
    int stride = gridDim.x * blockDim.x;
    for (; i < E; i += stride) {
        int d = dst[i];
        int p = atomicAdd(&cursor[d], 1);
        int j = offsets[d] + p;
        csr_src[j] = src[i];
        csr_w[j]   = w[i];
    }
}

// ---------------- z = relu(in @ Wl + bl), fused e (32->32) + t (TIN->8) ----------------
// RW: input row width/stride. e-part always reads cols [0,32). t-part reads cols [TOFF, TOFF+TIN).
template <int RW, int TIN, int TOFF>
__global__ __launch_bounds__(256) void z_kernel(
    const float* __restrict__ in,
    const float* __restrict__ we, const float* __restrict__ be,   // 32 x 32, 32
    const float* __restrict__ wt, const float* __restrict__ bt,   // TIN x 8, 8
    float* __restrict__ zcat, int n)
{
    __shared__ float sWe[32 * 32];
    __shared__ float sWt[TIN * 8];
    __shared__ float sBe[32];
    __shared__ float sBt[8];
    for (int i = threadIdx.x; i < 32 * 32; i += 256) sWe[i] = we[i];
    for (int i = threadIdx.x; i < TIN * 8; i += 256) sWt[i] = wt[i];
    if (threadIdx.x < 32) sBe[threadIdx.x] = be[threadIdx.x];
    if (threadIdx.x < 8)  sBt[threadIdx.x] = bt[threadIdx.x];
    __syncthreads();

    int node = blockIdx.x * 256 + threadIdx.x;
    if (node >= n) return;

    float row[RW];
    {
        const float4* rp = (const float4*)(in + (size_t)node * RW);
        #pragma unroll
        for (int q = 0; q < RW / 4; q++) {
            float4 v = rp[q];
            row[4*q] = v.x; row[4*q+1] = v.y; row[4*q+2] = v.z; row[4*q+3] = v.w;
        }
    }

    float accE[32];
    #pragma unroll
    for (int j = 0; j < 32; j++) accE[j] = sBe[j];
    #pragma unroll
    for (int i = 0; i < 32; i++) {
        float v = row[i];
        #pragma unroll
        for (int j = 0; j < 32; j++) accE[j] = fmaf(v, sWe[i * 32 + j], accE[j]);
    }

    float accT[8];
    #pragma unroll
    for (int j = 0; j < 8; j++) accT[j] = sBt[j];
    #pragma unroll
    for (int i = 0; i < TIN; i++) {
        float v = row[TOFF + i];
        #pragma unroll
        for (int j = 0; j < 8; j++) accT[j] = fmaf(v, sWt[i * 8 + j], accT[j]);
    }

    float4* zv = (float4*)(zcat + (size_t)node * 40);
    #pragma unroll
    for (int q = 0; q < 8; q++)
        zv[q] = make_float4(relu_(accE[4*q]), relu_(accE[4*q+1]),
                            relu_(accE[4*q+2]), relu_(accE[4*q+3]));
    zv[8] = make_float4(relu_(accT[0]), relu_(accT[1]), relu_(accT[2]), relu_(accT[3]));
    zv[9] = make_float4(relu_(accT[4]), relu_(accT[5]), relu_(accT[6]), relu_(accT[7]));
}

// ---------------- fused aggregate + finalize ----------------
// agg = (sum_{in-edges} w * z[src]) / (1 + sum w)
// outE = relu([row(0:32), aggE(32)] @ We(64x32) + be)
// outT = relu([row(TOFF:TOFF+TIN), aggT(8)] @ Wt((TIN+8)x8) + bt)
template <int RW, int TIN, int TOFF>
__global__ __launch_bounds__(256) void fin_kernel(
    const float* __restrict__ in,        // node features, stride RW
    const float* __restrict__ zcat,      // N x 40
    const int* __restrict__ offsets,
    const int* __restrict__ csr_src, const float* __restrict__ csr_w,
    const float* __restrict__ wre, const float* __restrict__ bre,   // 64 x 32, 32
    const float* __restrict__ wrt, const float* __restrict__ brt,   // (TIN+8) x 8, 8
    float* __restrict__ outbuf, int n)   // n rows, stride 40
{
    __shared__ float sWe[64 * 32];
    __shared__ float sWt[(TIN + 8) * 8];
    __shared__ float sBe[32];
    __shared__ float sBt[8];
    for (int i = threadIdx.x; i < 64 * 32; i += 256) sWe[i] = wre[i];
    for (int i = threadIdx.x; i < (TIN + 8) * 8; i += 256) sWt[i] = wrt[i];
    if (threadIdx.x < 32) sBe[threadIdx.x] = bre[threadIdx.x];
    if (threadIdx.x < 8)  sBt[threadIdx.x] = brt[threadIdx.x];
    __syncthreads();

    int node = blockIdx.x * 256 + threadIdx.x;
    if (node >= n) return;

    float acc[40];
    #pragma unroll
    for (int j = 0; j < 40; j++) acc[j] = 0.0f;
    float wsum = 1.0f;

    int e0 = offsets[node];
    int e1 = offsets[node + 1];
    for (int e = e0; e < e1; e++) {
        int sidx = csr_src[e];
        float w  = csr_w[e];
        const float4* zp = (const float4*)(zcat + (size_t)sidx * 40);
        #pragma unroll
        for (int q = 0; q < 10; q++) {
            float4 v = zp[q];
            acc[4*q]   = fmaf(w, v.x, acc[4*q]);
            acc[4*q+1] = fmaf(w, v.y, acc[4*q+1]);
            acc[4*q+2] = fmaf(w, v.z, acc[4*q+2]);
            acc[4*q+3] = fmaf(w, v.w, acc[4*q+3]);
        }
        wsum += w;
    }
    float inv = 1.0f / wsum;
    #pragma unroll
    for (int j = 0; j < 40; j++) acc[j] *= inv;

    float row[RW];
    {
        const float4* rp = (const float4*)(in + (size_t)node * RW);
        #pragma unroll
        for (int q = 0; q < RW / 4; q++) {
            float4 v = rp[q];
            row[4*q] = v.x; row[4*q+1] = v.y; row[4*q+2] = v.z; row[4*q+3] = v.w;
        }
    }

    float* op = outbuf + (size_t)node * 40;

    // e-part
    {
        float o[32];
        #pragma unroll
        for (int j = 0; j < 32; j++) o[j] = sBe[j];
        #pragma unroll
        for (int i = 0; i < 32; i++) {
            float v = row[i];
            #pragma unroll
            for (int j = 0; j < 32; j++) o[j] = fmaf(v, sWe[i * 32 + j], o[j]);
        }
        #pragma unroll
        for (int i = 0; i < 32; i++) {
            float v = acc[i];
            #pragma unroll
            for (int j = 0; j < 32; j++) o[j] = fmaf(v, sWe[(32 + i) * 32 + j], o[j]);
        }
        float4* ov = (float4*)op;
        #pragma unroll
        for (int q = 0; q < 8; q++)
            ov[q] = make_float4(relu_(o[4*q]), relu_(o[4*q+1]), relu_(o[4*q+2]), relu_(o[4*q+3]));
    }

    // t-part
    {
        float ot[8];
        #pragma unroll
        for (int j = 0; j < 8; j++) ot[j] = sBt[j];
        #pragma unroll
        for (int i = 0; i < TIN; i++) {
            float v = row[TOFF + i];
            #pragma unroll
            for (int j = 0; j < 8; j++) ot[j] = fmaf(v, sWt[i * 8 + j], ot[j]);
        }
        #pragma unroll
        for (int i = 0; i < 8; i++) {
            float v = acc[32 + i];
            #pragma unroll
            for (int j = 0; j < 8; j++) ot[j] = fmaf(v, sWt[(TIN + i) * 8 + j], ot[j]);
        }
        float4* ov = (float4*)op;
        ov[8] = make_float4(relu_(ot[0]), relu_(ot[1]), relu_(ot[2]), relu_(ot[3]));
        ov[9] = make_float4(relu_(ot[4]), relu_(ot[5]), relu_(ot[6]), relu_(ot[7]));
    }
}

// ---------------- loss ----------------

__device__ __forceinline__ void load40(const float* p, float* r) {
    const float4* v = (const float4*)p;
    #pragma unroll
    for (int q = 0; q < 10; q++) {
        float4 t = v[q];
        r[4*q] = t.x; r[4*q+1] = t.y; r[4*q+2] = t.z; r[4*q+3] = t.w;
    }
}

__device__ __forceinline__ float dot40(const float* a, const float* b) {
    float s = 0.0f;
    #pragma unroll
    for (int d = 0; d < 40; d++) s = fmaf(a[d], b[d], s);
    return s;
}

__device__ __forceinline__ void softmax5(const float l[5], float q[5]) {
    float m = l[0];
    #pragma unroll
    for (int c = 1; c < 5; c++) m = fmaxf(m, l[c]);
    float s = 0.0f;
    #pragma unroll
    for (int c = 0; c < 5; c++) { q[c] = expf(l[c] - m); s += q[c]; }
    float inv = 1.0f / s;
    #pragma unroll
    for (int c = 0; c < 5; c++) q[c] *= inv;
}

__device__ __forceinline__ float ent5(const float q[5]) {
    float e = 0.0f;
    #pragma unroll
    for (int c = 0; c < 5; c++) e += q[c] * logf(q[c] + 1e-20f);
    return e;
}

__device__ __forceinline__ float dot5(const float* a, const float* b) {
    float s = 0.0f;
    #pragma unroll
    for (int c = 0; c < 5; c++) s += a[c] * b[c];
    return s;
}

__global__ __launch_bounds__(256) void loss_kernel(
    const float* __restrict__ emb,       // BQ x 5 x 40
    const float* __restrict__ cent,      // 5 x 32
    const float* __restrict__ cent_t,    // 5 x 8
    float* __restrict__ out)
{
    __shared__ float sC[5 * 40];
    for (int i = threadIdx.x; i < 200; i += 256) {
        int c = i / 40, d = i % 40;
        sC[i] = (d < 32) ? cent[c * 32 + d] : cent_t[c * 8 + (d - 32)];
    }
    __syncthreads();

    int i = blockIdx.x * 256 + threadIdx.x;
    float contrib = 0.0f;
    if (i < BQ) {
        const float* base = emb + (size_t)i * 200;

        float ctr[40];
        load40(base, ctr);
        float l[5];
        #pragma unroll
        for (int c = 0; c < 5; c++) l[c] = dot40(ctr, sC + c * 40);
        float qc[5];
        softmax5(l, qc);
        float ent = ent5(qc);

        float rowv[40];
        load40(base + 40, rowv);
        float pd = dot40(ctr, rowv);
        #pragma unroll
        for (int c = 0; c < 5; c++) l[c] = dot40(rowv, sC + c * 40);
        float qp[5];
        softmax5(l, qp);
        float cpd = dot5(qc, qp);
        ent += ent5(qp);

        float nd = -1e30f, cnd = -1e30f;
        #pragma unroll
        for (int k = 0; k < 3; k++) {
            load40(base + (2 + k) * 40, rowv);
            nd = fmaxf(nd, dot40(ctr, rowv));
            #pragma unroll
            for (int c = 0; c < 5; c++) l[c] = dot40(rowv, sC + c * 40);
            float qn[5];
            softmax5(l, qn);
            cnd = fmaxf(cnd, dot5(qc, qn));
            ent += ent5(qn);
        }

        float mm  = fmaxf(nd - pd + 1.0f, 0.0f);
        float cmm = fmaxf(cnd - cpd + 1.0f, 0.0f);
        contrib = (mm + cmm) * (1.0f / (float)BQ) + 0.01f * (1.0f / (float)BS) * ent;
    }

    // wave reduction then one atomic per wave
    #pragma unroll
    for (int off = 32; off > 0; off >>= 1) contrib += __shfl_down(contrib, off);
    if ((threadIdx.x & 63) == 0) atomicAdd(out, contrib);
}

// ---------------- launch ----------------

extern "C" void kernel_launch(void* const* d_in, const int* in_sizes, int n_in,
                              void* d_out, int out_size, void* d_ws, size_t ws_size,
                              hipStream_t stream) {
    const float* x      = (const float*)d_in[0];
    const float* weight = (const float*)d_in[1];
    const float* e_w1l  = (const float*)d_in[2];
    const float* e_b1l  = (const float*)d_in[3];
    const float* e_w1r  = (const float*)d_in[4];
    const float* e_b1r  = (const float*)d_in[5];
    const float* e_w2l  = (const float*)d_in[6];
    const float* e_b2l  = (const float*)d_in[7];
    const float* e_w2r  = (const float*)d_in[8];
    const float* e_b2r  = (const float*)d_in[9];
    const float* t_w1l  = (const float*)d_in[10];
    const float* t_b1l  = (const float*)d_in[11];
    const float* t_w1r  = (const float*)d_in[12];
    const float* t_b1r  = (const float*)d_in[13];
    const float* t_w2l  = (const float*)d_in[14];
    const float* t_b2l  = (const float*)d_in[15];
    const float* t_w2r  = (const float*)d_in[16];
    const float* t_b2r  = (const float*)d_in[17];
    const float* cent   = (const float*)d_in[18];
    const float* cent_t = (const float*)d_in[19];
    const int*   eidx   = (const int*)d_in[20];

    const int E = in_sizes[20] / 2;
    const int N = in_sizes[0] / 32;
    const int* srcI = eidx;
    const int* dstI = eidx + E;
    float* out = (float*)d_out;

    char* p = (char*)d_ws;
    auto alloc = [&](size_t bytes) -> char* {
        char* r = p;
        p += (bytes + 255) & ~(size_t)255;
        return r;
    };
    float* zcat   = (float*)alloc((size_t)N * 40 * 4);
    float* hcat   = (float*)alloc((size_t)N * 40 * 4);
    float* emb    = (float*)alloc((size_t)BS * 40 * 4);
    int*   counts = (int*)alloc((size_t)N * 4);
    int*   offsets= (int*)alloc((size_t)(N + 1) * 4);
    int*   cursor = (int*)alloc((size_t)N * 4);
    int*   bsums  = (int*)alloc(4096);
    int*   boffs  = (int*)alloc(4096);
    int*   csr_src= (int*)alloc((size_t)E * 4);
    float* csr_w  = (float*)alloc((size_t)E * 4);
    (void)ws_size;

    hipMemsetAsync(counts, 0, (size_t)N * 4, stream);
    hipMemsetAsync(cursor, 0, (size_t)N * 4, stream);
    hipMemsetAsync(d_out, 0, sizeof(float), stream);

    const int nblk = (N + SCAN_T - 1) / SCAN_T;   // 489 <= 512

    hist_kernel<<<4096, 256, 0, stream>>>(dstI, counts, E);
    scan1_kernel<<<nblk, SCAN_T, 0, stream>>>(counts, N, offsets, bsums);
    scan2_kernel<<<1, 512, 0, stream>>>(bsums, nblk, boffs);
    scan3_kernel<<<nblk, SCAN_T, 0, stream>>>(offsets, boffs, N, E);
    fill_kernel<<<4096, 256, 0, stream>>>(srcI, dstI, weight, E, offsets, cursor, csr_src, csr_w);

    const int nb = (N + 255) / 256;
    // layer 1 (input x, 32-wide; t reads cols 0..31)
    z_kernel<32, 32, 0><<<nb, 256, 0, stream>>>(x, e_w1l, e_b1l, t_w1l, t_b1l, zcat, N);
    fin_kernel<32, 32, 0><<<nb, 256, 0, stream>>>(x, zcat, offsets, csr_src, csr_w,
                                                  e_w1r, e_b1r, t_w1r, t_b1r, hcat, N);
    // layer 2 (input hcat, 40-wide; t reads cols 32..39)
    z_kernel<40, 8, 32><<<nb, 256, 0, stream>>>(hcat, e_w2l, e_b2l, t_w2l, t_b2l, zcat, N);
    const int nb2 = (BS + 255) / 256;
    fin_kernel<40, 8, 32><<<nb2, 256, 0, stream>>>(hcat, zcat, offsets, csr_src, csr_w,
                                                   e_w2r, e_b2r, t_w2r, t_b2r, emb, BS);

    loss_kernel<<<(BQ + 255) / 256, 256, 0, stream>>>(emb, cent, cent_t, out);
}